// Round 11
// baseline (221.539 us; speedup 1.0000x reference)
//
#include <hip/hip_runtime.h>
#include <hip/hip_bf16.h>

#define BB 8
#define NN 1024
#define FIN 256
#define FOUT 64
#define NEGV (-9000000000000000.0f)

typedef __hip_bfloat16 bf16;
typedef short bf16x8 __attribute__((ext_vector_type(8)));
typedef unsigned short u16x8 __attribute__((ext_vector_type(8)));
typedef float f32x4 __attribute__((ext_vector_type(4)));

__device__ __forceinline__ float b2f(bf16 v) { return __bfloat162float(v); }
__device__ __forceinline__ float bu2f(unsigned short u) {
  union { unsigned int i; float f; } c;
  c.i = ((unsigned int)u) << 16;
  return c.f;
}
__device__ __forceinline__ unsigned short f2bu(float v) {
  bf16 t = __float2bfloat16(v);
  return *(unsigned short*)&t;
}

// async global->LDS, 16B per lane; LDS dest is wave-uniform base (+lane*16 by HW)
__device__ __forceinline__ void gload_lds16(const unsigned short* g,
                                            unsigned short* l) {
  __builtin_amdgcn_global_load_lds(
      (__attribute__((address_space(1))) void*)(unsigned long long)(const void*)g,
      (__attribute__((address_space(3))) void*)l, 16, 0, 0);
}

__device__ __forceinline__ float waveRedSum(float v) {
  for (int d = 32; d; d >>= 1) v += __shfl_down(v, d);
  return v;
}
__device__ __forceinline__ float waveRedMax(float v) {
  for (int d = 32; d; d >>= 1) v = fmaxf(v, __shfl_down(v, d));
  return v;
}
__device__ __forceinline__ float waveRedMin(float v) {
  for (int d = 32; d; d >>= 1) v = fminf(v, __shfl_down(v, d));
  return v;
}

__device__ __forceinline__ float blockSumF(float v, float* tmp) {
  __syncthreads();
  v = waveRedSum(v);
  if ((threadIdx.x & 63) == 0) tmp[threadIdx.x >> 6] = v;
  __syncthreads();
  return tmp[0] + tmp[1] + tmp[2] + tmp[3];
}
__device__ __forceinline__ float blockMaxF(float v, float* tmp) {
  __syncthreads();
  v = waveRedMax(v);
  if ((threadIdx.x & 63) == 0) tmp[threadIdx.x >> 6] = v;
  __syncthreads();
  return fmaxf(fmaxf(tmp[0], tmp[1]), fmaxf(tmp[2], tmp[3]));
}
__device__ __forceinline__ float blockMinF(float v, float* tmp) {
  __syncthreads();
  v = waveRedMin(v);
  if ((threadIdx.x & 63) == 0) tmp[threadIdx.x >> 6] = v;
  __syncthreads();
  return fminf(fminf(tmp[0], tmp[1]), fminf(tmp[2], tmp[3]));
}

__global__ void k_fill(unsigned short* o, int n, unsigned short pat) {
  int i = blockIdx.x * blockDim.x + threadIdx.x;
  int stride = gridDim.x * blockDim.x;
  for (; i < n; i += stride) o[i] = pat;
}

// fused: block 0 = dtype probe; blocks 1..96 zero sq/wh1/wh2; 97..128 zero rsum
__global__ void __launch_bounds__(256) k_setup(const unsigned short* xu,
                                               float* wsbase,
                                               float* flag,
                                               float* rsum) {
  const int tid = threadIdx.x;
  if (blockIdx.x == 0) {
    float mx = 0.0f, zc = 0.0f;
    for (int i = tid; i < 8192; i += 256) {
      unsigned short u = xu[i];
      float v = bu2f(u);
      if (u == 0 || u == 0x8000) zc += 1.0f;
      mx = fmaxf(mx, fabsf(v));
    }
    __shared__ float tmp[4];
    float gm = blockMaxF(mx, tmp);
    float gz = blockSumF(zc, tmp);
    if (tid == 0) flag[0] = (gm > 1.0e6f || gz > 2048.0f) ? 1.0f : 0.0f;
  } else if (blockIdx.x <= 96) {
    int i = (blockIdx.x - 1) * 256 + tid;
    wsbase[i] = 0.f;
  } else {
    int i = (int)(blockIdx.x - 97) * 256 + tid;
    rsum[i] = 0.f;
  }
}

// WT = W^T, split bf16 (hi/lo). One block per output row o (64 blocks).
__global__ void __launch_bounds__(256) k_wt(const void* Wv,
                                            const float* __restrict__ flag,
                                            unsigned short* __restrict__ WTh,
                                            unsigned short* __restrict__ WTl) {
  const bool f32m = (flag[0] != 0.0f);
  const int o = blockIdx.x;   // 0..63
  const int k = threadIdx.x;  // 0..255
  float v;
  if (f32m) v = ((const float*)Wv)[(size_t)k * FOUT + o];
  else      v = b2f(((const bf16*)Wv)[(size_t)k * FOUT + o]);
  unsigned short hh = f2bu(v);
  unsigned short hl = f2bu(v - bu2f(hh));
  WTh[o * FIN + k] = hh;
  WTl[o * FIN + k] = hl;
}

// h = x @ W via MFMA (split bf16, dual dtype x; W pre-transposed/split in WT).
// 256 blocks x 32 rows. sq/wh1/wh2 accumulated via atomics (zero-init'd).
__global__ void __launch_bounds__(256) k_h(const void* xv,
                                           const unsigned short* __restrict__ WTh,
                                           const unsigned short* __restrict__ WTl,
                                           const void* av,
                                           const float* __restrict__ flag,
                                           unsigned short* __restrict__ Hh,
                                           unsigned short* __restrict__ Hl,
                                           float* __restrict__ sq,
                                           float* __restrict__ wh1,
                                           float* __restrict__ wh2) {
  const int rowbase = blockIdx.x * 32;
  const bool f32m = (flag[0] != 0.0f);
  __shared__ unsigned short sm[12288];  // Ah 2048 | Al 2048 | Bh 4096 | Bl 4096
  const int tid = threadIdx.x;
  const int wave = tid >> 6, lane = tid & 63;
  const int wr = wave >> 1, wc = wave & 1;
  const int q = lane >> 4, ln = lane & 15;
  const int swz = (ln & 7);
  const int ar = tid >> 3;   // A stage: row 0..31
  const int acg = tid & 7;   // A stage: col-group
  f32x4 acc[2];
  acc[0] = (f32x4){0.f, 0.f, 0.f, 0.f};
  acc[1] = (f32x4){0.f, 0.f, 0.f, 0.f};
  for (int kc = 0; kc < 4; ++kc) {
    __syncthreads();
    // stage A (x tile 32x64) with store-side swizzle slot = cg ^ (r&7)
    {
      float v[8];
      if (f32m) {
        const float* xf = (const float*)xv +
                          (size_t)(rowbase + ar) * FIN + kc * 64 + acg * 8;
        float4 p0 = *(const float4*)xf;
        float4 p1 = *(const float4*)(xf + 4);
        v[0] = p0.x; v[1] = p0.y; v[2] = p0.z; v[3] = p0.w;
        v[4] = p1.x; v[5] = p1.y; v[6] = p1.z; v[7] = p1.w;
      } else {
        const unsigned short* xb = (const unsigned short*)xv +
                                   (size_t)(rowbase + ar) * FIN + kc * 64 + acg * 8;
        ushort4 p0 = *(const ushort4*)xb;
        ushort4 p1 = *(const ushort4*)(xb + 4);
        v[0] = bu2f(p0.x); v[1] = bu2f(p0.y); v[2] = bu2f(p0.z); v[3] = bu2f(p0.w);
        v[4] = bu2f(p1.x); v[5] = bu2f(p1.y); v[6] = bu2f(p1.z); v[7] = bu2f(p1.w);
      }
      unsigned short hs[8], ls[8];
      for (int e = 0; e < 8; ++e) {
        hs[e] = f2bu(v[e]);
        ls[e] = f2bu(v[e] - bu2f(hs[e]));
      }
      int base = ar * 64 + ((acg ^ (ar & 7)) << 3);
      ushort4 h0, h1, l0, l1;
      h0.x = hs[0]; h0.y = hs[1]; h0.z = hs[2]; h0.w = hs[3];
      h1.x = hs[4]; h1.y = hs[5]; h1.z = hs[6]; h1.w = hs[7];
      l0.x = ls[0]; l0.y = ls[1]; l0.z = ls[2]; l0.w = ls[3];
      l1.x = ls[4]; l1.y = ls[5]; l1.z = ls[6]; l1.w = ls[7];
      *(ushort4*)&sm[base] = h0;
      *(ushort4*)&sm[base + 4] = h1;
      *(ushort4*)&sm[2048 + base] = l0;
      *(ushort4*)&sm[2048 + base + 4] = l1;
    }
    // stage B (W^T tile: 64 o-rows x 64 k) from preformatted WT, 2 slots/thread
    for (int u = 0; u < 2; ++u) {
      int s = tid + (u << 8);
      int br = s >> 3, bcg = s & 7;  // br = o row, bcg = k col-group
      const unsigned short* th = WTh + (size_t)br * FIN + kc * 64 + bcg * 8;
      const unsigned short* tl = WTl + (size_t)br * FIN + kc * 64 + bcg * 8;
      ushort4 h0 = *(const ushort4*)th;
      ushort4 h1 = *(const ushort4*)(th + 4);
      ushort4 l0 = *(const ushort4*)tl;
      ushort4 l1 = *(const ushort4*)(tl + 4);
      int base = br * 64 + ((bcg ^ (br & 7)) << 3);
      *(ushort4*)&sm[4096 + base] = h0;
      *(ushort4*)&sm[4096 + base + 4] = h1;
      *(ushort4*)&sm[8192 + base] = l0;
      *(ushort4*)&sm[8192 + base + 4] = l1;
    }
    __syncthreads();
    for (int ks = 0; ks < 2; ++ks) {
      const int gq = ((ks * 4 + q) ^ swz) << 3;
      bf16x8 fah = *(const bf16x8*)&sm[(wr * 16 + ln) * 64 + gq];
      bf16x8 fal = *(const bf16x8*)&sm[2048 + (wr * 16 + ln) * 64 + gq];
      for (int j = 0; j < 2; ++j) {
        int boff = (wc * 32 + j * 16 + ln) * 64 + gq;
        bf16x8 fbh = *(const bf16x8*)&sm[4096 + boff];
        bf16x8 fbl = *(const bf16x8*)&sm[8192 + boff];
        acc[j] = __builtin_amdgcn_mfma_f32_16x16x32_bf16(fah, fbh, acc[j], 0, 0, 0);
        acc[j] = __builtin_amdgcn_mfma_f32_16x16x32_bf16(fah, fbl, acc[j], 0, 0, 0);
        acc[j] = __builtin_amdgcn_mfma_f32_16x16x32_bf16(fal, fbh, acc[j], 0, 0, 0);
      }
    }
  }
  // epilogue: h store (split) + row reductions (sq, wh1, wh2) via atomics
  float a1v[2], a2v[2];
  for (int j = 0; j < 2; ++j) {
    int o = wc * 32 + j * 16 + ln;
    if (f32m) {
      a1v[j] = ((const float*)av)[o];
      a2v[j] = ((const float*)av)[FOUT + o];
    } else {
      a1v[j] = b2f(((const bf16*)av)[o]);
      a2v[j] = b2f(((const bf16*)av)[FOUT + o]);
    }
  }
  float s_sq[4] = {0.f, 0.f, 0.f, 0.f};
  float s_w1[4] = {0.f, 0.f, 0.f, 0.f};
  float s_w2[4] = {0.f, 0.f, 0.f, 0.f};
  for (int j = 0; j < 2; ++j) {
    int o = wc * 32 + j * 16 + ln;
    for (int reg = 0; reg < 4; ++reg) {
      int bn = rowbase + wr * 16 + q * 4 + reg;
      float hv = acc[j][reg];
      unsigned short hh = f2bu(hv);
      unsigned short hl = f2bu(hv - bu2f(hh));
      Hh[(size_t)bn * FOUT + o] = hh;
      Hl[(size_t)bn * FOUT + o] = hl;
      s_sq[reg] += hv * hv;
      s_w1[reg] += hv * a1v[j];
      s_w2[reg] += hv * a2v[j];
    }
  }
  for (int reg = 0; reg < 4; ++reg) {
    float v1 = s_sq[reg], v2 = s_w1[reg], v3 = s_w2[reg];
    for (int d = 1; d < 16; d <<= 1) {
      v1 += __shfl_xor(v1, d);
      v2 += __shfl_xor(v2, d);
      v3 += __shfl_xor(v3, d);
    }
    if (ln == 0) {
      int bn = rowbase + wr * 16 + q * 4 + reg;
      atomicAdd(&sq[bn], v1);
      atomicAdd(&wh1[bn], v2);
      atomicAdd(&wh2[bn], v3);
    }
  }
}

// Pass 1: rowsums of M = exp(-dist) via MFMA (no stores). Proven k_g structure.
__global__ void __launch_bounds__(256) k_g0(const unsigned short* __restrict__ Hhp,
                                            const unsigned short* __restrict__ Hlp,
                                            const float* __restrict__ sq,
                                            float* __restrict__ rsum) {
  const int bid = blockIdx.x;
  const int z = bid & 7;
  const int t6 = bid >> 3;
  const int tr = (t6 >> 3) * 128, tc = (t6 & 7) * 128;
  const float* sqb = sq + (z << 10);
  float* rsb = rsum + (z << 10);
  __shared__ unsigned short sm[32768];
  const int tid = threadIdx.x;
  const int wave = tid >> 6, lane = tid & 63;
  const int wm = (wave >> 1) * 64, wn = (wave & 1) * 64;
  const int q = lane >> 4, ln = lane & 15;
  const int rl = lane >> 3;
  const int gcol = ((lane & 7) ^ rl) << 3;
  const size_t HB = (size_t)z * NN * FOUT;
  const unsigned short* gp0;
  unsigned short* lb;
  if (wave == 0)      { gp0 = Hhp + HB + (size_t)tr * FOUT; lb = sm; }
  else if (wave == 1) { gp0 = Hlp + HB + (size_t)tr * FOUT; lb = sm + 8192; }
  else if (wave == 2) { gp0 = Hhp + HB + (size_t)tc * FOUT; lb = sm + 16384; }
  else                { gp0 = Hlp + HB + (size_t)tc * FOUT; lb = sm + 24576; }
  for (int t = 0; t < 16; ++t)
    gload_lds16(gp0 + (size_t)(t * 8 + rl) * FOUT + gcol, lb + t * 512);
  f32x4 acc[4][4];
  for (int i = 0; i < 4; ++i)
    for (int j = 0; j < 4; ++j) acc[i][j] = (f32x4){0.f, 0.f, 0.f, 0.f};
  __syncthreads();
  const int swz = (ln & 7);
  for (int ks = 0; ks < 2; ++ks) {
    const int gq = ((ks * 4 + q) ^ swz) << 3;
    bf16x8 fah[4], fal[4], fbh[4], fbl[4];
    for (int i = 0; i < 4; ++i) {
      int off = (wm + i * 16 + ln) * 64 + gq;
      fah[i] = *(const bf16x8*)&sm[off];
      fal[i] = *(const bf16x8*)&sm[8192 + off];
    }
    for (int j = 0; j < 4; ++j) {
      int off = (wn + j * 16 + ln) * 64 + gq;
      fbh[j] = *(const bf16x8*)&sm[16384 + off];
      fbl[j] = *(const bf16x8*)&sm[24576 + off];
    }
    for (int i = 0; i < 4; ++i)
      for (int j = 0; j < 4; ++j) {
        acc[i][j] = __builtin_amdgcn_mfma_f32_16x16x32_bf16(fah[i], fbh[j], acc[i][j], 0, 0, 0);
        acc[i][j] = __builtin_amdgcn_mfma_f32_16x16x32_bf16(fah[i], fbl[j], acc[i][j], 0, 0, 0);
        acc[i][j] = __builtin_amdgcn_mfma_f32_16x16x32_bf16(fal[i], fbh[j], acc[i][j], 0, 0, 0);
      }
  }
  float rs[4] = {0.f, 0.f, 0.f, 0.f};
  for (int i = 0; i < 4; ++i) {
    int m0 = tr + wm + i * 16 + q * 4;
    float sm0[4];
    for (int reg = 0; reg < 4; ++reg) sm0[reg] = sqb[m0 + reg];
    for (int j = 0; j < 4; ++j) {
      int n = tc + wn + j * 16 + ln;
      float sn = sqb[n];
      for (int reg = 0; reg < 4; ++reg) {
        int m = m0 + reg;
        float d2 = sm0[reg] + sn - 2.0f * acc[i][j][reg];
        float v = (m == n) ? 1.0f : ((d2 > 0.0f) ? expf(-sqrtf(d2)) : 1.0f);
        rs[j] += v;
      }
    }
  }
  for (int j = 0; j < 4; ++j) {
    float v = rs[j];
    v += __shfl_xor(v, 16);
    v += __shfl_xor(v, 32);
    if (q == 0) {
      int n = tc + wn + j * 16 + ln;
      atomicAdd(&rsb[n], v);
    }
  }
}

// dcl[i] = max(rsum,1e-12); isq[i] = 1/sqrt(dcl)
__global__ void __launch_bounds__(256) k_scal(const float* __restrict__ rsum,
                                              float* __restrict__ dcl,
                                              float* __restrict__ isq) {
  int i = blockIdx.x * blockDim.x + threadIdx.x;
  if (i < BB * NN) {
    float r = fmaxf(rsum[i], 1e-12f);
    dcl[i] = r;
    isq[i] = 1.0f / sqrtf(r);
  }
}

// Pass 2: W = D^-1/2 M D^-1/2 via MFMA recompute; coalesced LDS-transpose
// epilogue (straight [m][n] stores, 64B-contiguous). Proven in round 8.
__global__ void __launch_bounds__(256) k_gw(const unsigned short* __restrict__ Hhp,
                                            const unsigned short* __restrict__ Hlp,
                                            const float* __restrict__ sq,
                                            const float* __restrict__ isq,
                                            unsigned short* __restrict__ Wh,
                                            unsigned short* __restrict__ Wl) {
  const int bid = blockIdx.x;
  const int z = bid & 7;
  const int t6 = bid >> 3;
  const int tr = (t6 >> 3) * 128, tc = (t6 & 7) * 128;
  const size_t MAT = (size_t)NN * NN;
  const float* sqb = sq + (z << 10);
  const float* isqb = isq + (z << 10);
  unsigned short* whb = Wh + z * MAT;
  unsigned short* wlb = Wl + z * MAT;
  __shared__ unsigned short sm[32768];
  const int tid = threadIdx.x;
  const int wave = tid >> 6, lane = tid & 63;
  const int wm = (wave >> 1) * 64, wn = (wave & 1) * 64;
  const int q = lane >> 4, ln = lane & 15;
  const int rl = lane >> 3;
  const int gcol = ((lane & 7) ^ rl) << 3;
  const size_t HB = (size_t)z * NN * FOUT;
  const unsigned short* gp0;
  unsigned short* lb;
  if (wave == 0)      { gp0 = Hhp + HB + (size_t)tr * FOUT; lb = sm; }
  else if (wave == 1) { gp0 = Hlp + HB + (size_t)tr * FOUT; lb = sm + 8192; }
  else if (wave == 2) { gp0 = Hhp + HB + (size_t)tc * FOUT; lb = sm + 16384; }
  else                { gp0 = Hlp + HB + (size_t)tc * FOUT; lb = sm + 24576; }
  for (int t = 0; t < 16; ++t)
    gload_lds16(gp0 + (size_t)(t * 8 + rl) * FOUT + gcol, lb + t * 512);
  f32x4 acc[4][4];
  for (int i = 0; i < 4; ++i)
    for (int j = 0; j < 4; ++j) acc[i][j] = (f32x4){0.f, 0.f, 0.f, 0.f};
  __syncthreads();
  const int swz = (ln & 7);
  for (int ks = 0; ks < 2; ++ks) {
    const int gq = ((ks * 4 + q) ^ swz) << 3;
    bf16x8 fah[4], fal[4], fbh[4], fbl[4];
    for (int i = 0; i < 4; ++i) {
      int off = (wm + i * 16 + ln) * 64 + gq;
      fah[i] = *(const bf16x8*)&sm[off];
      fal[i] = *(const bf16x8*)&sm[8192 + off];
    }
    for (int j = 0; j < 4; ++j) {
      int off = (wn + j * 16 + ln) * 64 + gq;
      fbh[j] = *(const bf16x8*)&sm[16384 + off];
      fbl[j] = *(const bf16x8*)&sm[24576 + off];
    }
    for (int i = 0; i < 4; ++i)
      for (int j = 0; j < 4; ++j) {
        acc[i][j] = __builtin_amdgcn_mfma_f32_16x16x32_bf16(fah[i], fbh[j], acc[i][j], 0, 0, 0);
        acc[i][j] = __builtin_amdgcn_mfma_f32_16x16x32_bf16(fah[i], fbl[j], acc[i][j], 0, 0, 0);
        acc[i][j] = __builtin_amdgcn_mfma_f32_16x16x32_bf16(fal[i], fbh[j], acc[i][j], 0, 0, 0);
      }
  }
  // ---- coalesced epilogue ----
  __syncthreads();  // all waves done reading sm fragments; reuse sm as f32 pads
  float* wtile = (float*)sm + wave * 1104;  // [16][69] f32 per wave (4416 B)
  const int r = lane >> 2;        // out row within 16-row slab
  const int a = lane & 3;         // col-chunk selector
  for (int i = 0; i < 4; ++i) {
    for (int j = 0; j < 4; ++j)
      for (int reg = 0; reg < 4; ++reg)
        wtile[(q * 4 + reg) * 69 + j * 16 + ln] = acc[i][j][reg];
    // wave-private region: compiler's lgkmcnt orders ds_write -> ds_read
    const int m = tr + wm + i * 16 + r;
    const float vsm = sqb[m];
    const float vim = isqb[m];
    const int nbase = tc + wn;
    u16x8 hv[2], lv[2];
    for (int ch = 0; ch < 2; ++ch) {
      const int coff = ch * 32 + a * 8;  // cols {8a, 32+8a}
      const int n0 = nbase + coff;
      float4 sn0 = *(const float4*)&sqb[n0];
      float4 sn1 = *(const float4*)&sqb[n0 + 4];
      float4 in0 = *(const float4*)&isqb[n0];
      float4 in1 = *(const float4*)&isqb[n0 + 4];
      float snv[8] = {sn0.x, sn0.y, sn0.z, sn0.w, sn1.x, sn1.y, sn1.z, sn1.w};
      float inv[8] = {in0.x, in0.y, in0.z, in0.w, in1.x, in1.y, in1.z, in1.w};
      for (int c = 0; c < 8; ++c) {
        float g = wtile[r * 69 + coff + c];
        float d2 = vsm + snv[c] - 2.0f * g;
        int n = n0 + c;
        float v = (m == n) ? 1.0f : ((d2 > 0.0f) ? expf(-sqrtf(d2)) : 1.0f);
        float vw = v * vim * inv[c];
        unsigned short hh = f2bu(vw);
        hv[ch][c] = hh;
        lv[ch][c] = f2bu(vw - bu2f(hh));
      }
    }
    unsigned short* wp = &whb[(size_t)m * NN + nbase];
    unsigned short* lp = &wlb[(size_t)m * NN + nbase];
    *(u16x8*)&wp[a * 8] = hv[0];
    *(u16x8*)&wp[32 + a * 8] = hv[1];
    *(u16x8*)&lp[a * 8] = lv[0];
    *(u16x8*)&lp[32 + a * 8] = lv[1];
    __builtin_amdgcn_s_waitcnt(0);  // drain lgkm before next slab overwrites wtile
  }
}

// MFMA GEMM1: U = W^2 (symmetric). 64x128 triangle tiles (ri <= 2cj+1).
// Balanced staging (12 gload_lds per wave) + slab epilogue.
__global__ void __launch_bounds__(256) k_mm1(
    const unsigned short* __restrict__ Wh, const unsigned short* __restrict__ Wl,
    unsigned short* __restrict__ Uh, unsigned short* __restrict__ Ul) {
  const int bid = blockIdx.x;
  const int z = bid & 7;
  int p = bid >> 3;  // 0..71
  int cj = 0, rem = p;
  while (rem >= 2 * cj + 2) { rem -= 2 * cj + 2; ++cj; }
  const int ri = rem;  // 0..2cj+1
  const int r0 = ri * 64, c0 = cj * 128;
  const size_t MAT = (size_t)NN * NN;
  __shared__ unsigned short sm[24576];  // staging, then slab G[64][129] f32
  const int tid = threadIdx.x;
  const int wave = tid >> 6, lane = tid & 63;
  const int wm = (wave >> 1) * 32, wn = (wave & 1) * 64;
  const int q = lane >> 4, ln = lane & 15;
  const int rl = lane >> 3;
  const int gcol = ((lane & 7) ^ rl) << 3;
  const unsigned short* gAh = Wh + z * MAT + (size_t)r0 * NN;
  const unsigned short* gAl = Wl + z * MAT + (size_t)r0 * NN;
  const unsigned short* gBh = Wh + z * MAT + (size_t)c0 * NN;
  const unsigned short* gBl = Wl + z * MAT + (size_t)c0 * NN;
  f32x4 acc[2][4];
  for (int i = 0; i < 2; ++i)
    for (int j = 0; j < 4; ++j) acc[i][j] = (f32x4){0.f, 0.f, 0.f, 0.f};
  const int swz = (ln & 7);
  for (int kc = 0; kc < NN; kc += 64) {
    __syncthreads();
    const int off = kc + gcol;
    if (wave == 0) {
      for (int t = 0; t < 8; ++t)
        gload_lds16(gAh + off + (size_t)(t * 8 + rl) * NN, sm + t * 512);
      for (int t = 0; t < 4; ++t)
        gload_lds16(gBh + off + (size_t)(t * 8 + rl) * NN, sm + 8192 + t * 512);
    } else if (wave == 1) {
      for (int t = 0; t < 8; ++t)
        gload_lds16(gAl + off + (size_t)(t * 8 + rl) * NN, sm + 4096 + t * 512);
      for (int t = 4; t < 8; ++t)
        gload_lds16(gBh + off + (size_t)(t * 8 + rl) * NN, sm + 8192 + t * 512);
    } else if (wave == 2) {
      for (int t = 8; t < 16; ++t)
        gload_lds16(gBh + off + (size_t)(t * 8 + rl) * NN, sm + 8192 + t * 512);
      for (int t = 0; t < 4; ++t)
        gload_lds16(gBl + off + (size_t)(t * 8 + rl) * NN, sm + 16384 + t * 512);
    } else {
      for (int t = 4; t < 16; ++t)
        gload_lds16(gBl + off + (size_t)(t * 8 + rl) * NN, sm + 16384 + t * 512);
    }
    __syncthreads();
    for (int ks = 0; ks < 2; ++ks) {
      const int gq = ((ks * 4 + q) ^ swz) << 3;
      bf16x8 fah[2], fal[2], fbh[4], fbl[4];
      for (int i = 0; i < 2; ++i) {
        int o2 = (wm + i * 16 + ln) * 64 + gq;
        fah[i] = *(const bf16x8*)&sm[o2];
        fal[i] = *(const bf16x8*)&sm[4096 + o2];
      }
      for (int j = 0; j < 4; ++j) {
        int o2 = (wn + j * 16 + ln) * 64 + gq;
        fbh[j] = *(const bf16x8*)&sm[8192 + o2];
        fbl[j] = *(const bf16x8*)&sm[16384 + o2];
      }
      for (int i = 0; i < 2; ++i)
        for (int j = 0; j < 4; ++j) {
          acc[i][j] = __builtin_amdgcn_mfma_f32_16x16x32_bf16(fah[i], fbh[j], acc[i][j], 0, 0, 0);
          acc[i][j] = __builtin_amdgcn_mfma_f32_16x16x32_bf16(fah[i], fbl[j], acc[i][j], 0, 0, 0);
          acc[i][j] = __builtin_amdgcn_mfma_f32_16x16x32_bf16(fal[i], fbh[j], acc[i][j], 0, 0, 0);
        }
    }
  }
  // dump acc to slab
  __syncthreads();
  float* G = (float*)sm;  // [64][129] = 33024 B <= 49152 B
  for (int i = 0; i < 2; ++i) {
    int rloc = wm + i * 16 + q * 4;
    for (int j = 0; j < 4; ++j) {
      int nloc = wn + j * 16 + ln;
      for (int reg = 0; reg < 4; ++reg)
        G[(rloc + reg) * 129 + nloc] = acc[i][j][reg];
    }
  }
  __syncthreads();
  unsigned short* cth = Uh + z * MAT;
  unsigned short* ctl = Ul + z * MAT;
  const bool mirror = ((ri >> 1) < cj);  // block-uniform, == old per-elem guard
  {
    const int r = tid >> 2;
    const int cb8 = (tid & 3) * 8;
    unsigned short* ph = &cth[(size_t)(r0 + r) * NN + c0 + cb8];
    unsigned short* pl = &ctl[(size_t)(r0 + r) * NN + c0 + cb8];
    const float* gr = &G[r * 129 + cb8];
    for (int ch = 0; ch < 4; ++ch) {
      u16x8 hv, lv;
      for (int c = 0; c < 8; ++c) {
        float v = gr[ch * 32 + c];
        unsigned short hh = f2bu(v);
        hv[c] = hh;
        lv[c] = f2bu(v - bu2f(hh));
      }
      *(u16x8*)&ph[ch * 32] = hv;
      *(u16x8*)&pl[ch * 32] = lv;
    }
  }
  if (mirror) {
    const int n = tid >> 1;
    const int cb8 = (tid & 1) * 8;
    unsigned short* ph = &cth[(size_t)(c0 + n) * NN + r0 + cb8];
    unsigned short* pl = &ctl[(size_t)(c0 + n) * NN + r0 + cb8];
    for (int ch = 0; ch < 4; ++ch) {
      u16x8 hv, lv;
      for (int c = 0; c < 8; ++c) {
        float v = G[(cb8 + ch * 16 + c) * 129 + n];
        unsigned short hh = f2bu(v);
        hv[c] = hh;
        lv[c] = f2bu(v - bu2f(hh));
      }
      *(u16x8*)&ph[ch * 16] = hv;
      *(u16x8*)&pl[ch * 16] = lv;
    }
  }
}

// MFMA GEMM2: W^3 = U * W with FUSED combine. Balanced staging + slab epilogue.
__global__ void __launch_bounds__(256) k_mm2(
    const unsigned short* __restrict__ Uh, const unsigned short* __restrict__ Ul,
    const unsigned short* __restrict__ Wh, const unsigned short* __restrict__ Wl,
    const float* __restrict__ dcl, const float* __restrict__ isq,
    float* __restrict__ S) {
  const int bid = blockIdx.x;
  const int z = bid & 7;
  int p = bid >> 3;
  int cj = 0, rem = p;
  while (rem >= 2 * cj + 2) { rem -= 2 * cj + 2; ++cj; }
  const int ri = rem;
  const int r0 = ri * 64, c0 = cj * 128;
  const size_t MAT = (size_t)NN * NN;
  __shared__ unsigned short sm[24576];
  const int tid = threadIdx.x;
  const int wave = tid >> 6, lane = tid & 63;
  const int wm = (wave >> 1) * 32, wn = (wave & 1) * 64;
  const int q = lane >> 4, ln = lane & 15;
  const int rl = lane >> 3;
  const int gcol = ((lane & 7) ^ rl) << 3;
  const unsigned short* gAh = Uh + z * MAT + (size_t)r0 * NN;
  const unsigned short* gAl = Ul + z * MAT + (size_t)r0 * NN;
  const unsigned short* gBh = Wh + z * MAT + (size_t)c0 * NN;
  const unsigned short* gBl = Wl + z * MAT + (size_t)c0 * NN;
  f32x4 acc[2][4];
  for (int i = 0; i < 2; ++i)
    for (int j = 0; j < 4; ++j) acc[i][j] = (f32x4){0.f, 0.f, 0.f, 0.f};
  const int swz = (ln & 7);
  for (int kc = 0; kc < NN; kc += 64) {
    __syncthreads();
    const int off = kc + gcol;
    if (wave == 0) {
      for (int t = 0; t < 8; ++t)
        gload_lds16(gAh + off + (size_t)(t * 8 + rl) * NN, sm + t * 512);
      for (int t = 0; t < 4; ++t)
        gload_lds16(gBh + off + (size_t)(t * 8 + rl) * NN, sm + 8192 + t * 512);
    } else if (wave == 1) {
      for (int t = 0; t < 8; ++t)
        gload_lds16(gAl + off + (size_t)(t * 8 + rl) * NN, sm + 4096 + t * 512);
      for (int t = 4; t < 8; ++t)
        gload_lds16(gBh + off + (size_t)(t * 8 + rl) * NN, sm + 8192 + t * 512);
    } else if (wave == 2) {
      for (int t = 8; t < 16; ++t)
        gload_lds16(gBh + off + (size_t)(t * 8 + rl) * NN, sm + 8192 + t * 512);
      for (int t = 0; t < 4; ++t)
        gload_lds16(gBl + off + (size_t)(t * 8 + rl) * NN, sm + 16384 + t * 512);
    } else {
      for (int t = 4; t < 16; ++t)
        gload_lds16(gBl + off + (size_t)(t * 8 + rl) * NN, sm + 16384 + t * 512);
    }
    __syncthreads();
    for (int ks = 0; ks < 2; ++ks) {
      const int gq = ((ks * 4 + q) ^ swz) << 3;
      bf16x8 fah[2], fal[2], fbh[4], fbl[4];
      for (int i = 0; i < 2; ++i) {
        int o2 = (wm + i * 16 + ln) * 64 + gq;
        fah[i] = *(const bf16x8*)&sm[o2];
        fal[i] = *(const bf16x8*)&sm[4096 + o2];
      }
      for (int j = 0; j < 4; ++j) {
        int o2 = (wn + j * 16 + ln) * 64 + gq;
        fbh[j] = *(const bf16x8*)&sm[8192 + o2];
        fbl[j] = *(const bf16x8*)&sm[16384 + o2];
      }
      for (int i = 0; i < 2; ++i)
        for (int j = 0; j < 4; ++j) {
          acc[i][j] = __builtin_amdgcn_mfma_f32_16x16x32_bf16(fah[i], fbh[j], acc[i][j], 0, 0, 0);
          acc[i][j] = __builtin_amdgcn_mfma_f32_16x16x32_bf16(fah[i], fbl[j], acc[i][j], 0, 0, 0);
          acc[i][j] = __builtin_amdgcn_mfma_f32_16x16x32_bf16(fal[i], fbh[j], acc[i][j], 0, 0, 0);
        }
    }
  }
  // dump acc to slab
  __syncthreads();
  float* G = (float*)sm;  // [64][129]
  for (int i = 0; i < 2; ++i) {
    int rloc = wm + i * 16 + q * 4;
    for (int j = 0; j < 4; ++j) {
      int nloc = wn + j * 16 + ln;
      for (int reg = 0; reg < 4; ++reg)
        G[(rloc + reg) * 129 + nloc] = acc[i][j][reg];
    }
  }
  __syncthreads();
  const unsigned short* wh = Wh + z * MAT;
  const unsigned short* wl = Wl + z * MAT;
  const unsigned short* uh = Uh + z * MAT;
  const unsigned short* ul = Ul + z * MAT;
  const float* dz = dcl + (z << 10);
  const float* iz = isq + (z << 10);
  float* Sb = S + z * MAT;
  const bool mirror = ((ri >> 1) < cj);
  {
    const int r = tid >> 2;
    const int cb8 = (tid & 3) * 8;
    const int m = r0 + r;
    const float dmv = dz[m];
    const float imv = iz[m];
    float* gr = &G[r * 129 + cb8];
    for (int ch = 0; ch < 4; ++ch) {
      const int cg = c0 + cb8 + ch * 32;
      u16x8 w8h = *(const u16x8*)&wh[(size_t)m * NN + cg];
      u16x8 w8l = *(const u16x8*)&wl[(size_t)m * NN + cg];
      u16x8 u8h = *(const u16x8*)&uh[(size_t)m * NN + cg];
      u16x8 u8l = *(const u16x8*)&ul[(size_t)m * NN + cg];
      float4 d0 = *(const float4*)&dz[cg];
      float4 d1 = *(const float4*)&dz[cg + 4];
      float4 i0 = *(const float4*)&iz[cg];
      float4 i1 = *(const float4*)&iz[cg + 4];
      float dnv[8] = {d0.x, d0.y, d0.z, d0.w, d1.x, d1.y, d1.z, d1.w};
      float inv[8] = {i0.x, i0.y, i0.z, i0.w, i1.x, i1.y, i1.z, i1.w};
      float sv[8];
      for (int c = 0; c < 8; ++c) {
        float wv = bu2f(w8h[c]) + bu2f(w8l[c]);
        float uv = bu2f(u8h[c]) + bu2f(u8l[c]);
        float pf = 0.5f * (dmv + dnv[c]) * imv * inv[c];
        sv[c] = pf * (wv + 0.8f * uv + 0.64f * gr[ch * 32 + c]);
      }
      *(float4*)&Sb[(size_t)m * NN + cg] = make_float4(sv[0], sv[1], sv[2], sv[3]);
      *(float4*)&Sb[(size_t)m * NN + cg + 4] = make_float4(sv[4], sv[5], sv[6], sv[7]);
      if (mirror)
        for (int c = 0; c < 8; ++c) gr[ch * 32 + c] = sv[c];
    }
  }
  if (mirror) {
    __syncthreads();
    const int n = tid >> 1;
    const int cb8 = (tid & 1) * 8;
    float* Sr = &Sb[(size_t)(c0 + n) * NN + r0 + cb8];
    for (int ch = 0; ch < 4; ++ch) {
      float sv[8];
      for (int c = 0; c < 8; ++c)
        sv[c] = G[(cb8 + ch * 16 + c) * 129 + n];
      *(float4*)&Sr[ch * 16] = make_float4(sv[0], sv[1], sv[2], sv[3]);
      *(float4*)&Sr[ch * 16 + 4] = make_float4(sv[4], sv[5], sv[6], sv[7]);
    }
  }
}

// thr[b] = min(diag) - mean(diag[:-1] - offdiag)
__global__ void __launch_bounds__(256) k_thr(const float* __restrict__ S,
                                             float* __restrict__ thr) {
  const int b = blockIdx.x;
  const float* Sb = S + (size_t)b * NN * NN;
  const int tid = threadIdx.x;
  float mn = 3.0e38f;
  float rsum = 0.f;
  for (int n = tid; n < NN; n += 256) {
    float d = Sb[(size_t)n * NN + n];
    mn = fminf(mn, d);
    if (n < NN - 1) rsum += d - Sb[(size_t)n * NN + n + 1];
  }
  __shared__ float tmp[4];
  float mtot = blockMinF(mn, tmp);
  float stot = blockSumF(rsum, tmp);
  if (tid == 0) thr[b] = mtot - stot / 1023.0f;
}

// Fused stats + out: 256-thread blocks, one per n; thread t owns
// m in {t, t+256, t+512, t+768} x 8 batches = 32 att values in registers.
__global__ void __launch_bounds__(256) k_so(const float* __restrict__ S,
                                            const float* __restrict__ thr,
                                            const float* __restrict__ wh1,
                                            const float* __restrict__ wh2,
                                            const float* __restrict__ flag,
                                            void* outv) {
  const int n = blockIdx.x;
  const int tid = threadIdx.x;
  const int wid = tid >> 6;
  const bool f32m = (flag[0] != 0.0f);
  __shared__ double dred[8];   // [2][4 waves]
  __shared__ float fred[32];   // [8 b][4 waves]
  __shared__ float sres[2];
  float att[8][4];
  double s1 = 0.0, s2 = 0.0;
  for (int b = 0; b < 8; ++b) {
    const float t = thr[b];
    const float w1 = wh1[(b << 10) + n];
    const float* Srow = S + ((size_t)(b << 10) + n) * NN;
    const float* w2p = wh2 + (b << 10);
    for (int k = 0; k < 4; ++k) {
      float sv = Srow[tid + (k << 8)];
      float e = w1 + w2p[tid + (k << 8)];
      e = (e > 0.f) ? e : 0.01f * e;
      float a = (sv > t) ? e : NEGV;
      att[b][k] = a;
      s1 += (double)a;
      s2 += (double)a * (double)a;
    }
  }
  for (int d = 32; d; d >>= 1) {
    s1 += __shfl_down(s1, d);
    s2 += __shfl_down(s2, d);
  }
  if ((tid & 63) == 0) {
    dred[wid] = s1;
    dred[4 + wid] = s2;
  }
  __syncthreads();
  if (tid == 0) {
    double a = dred[0] + dred[1] + dred[2] + dred[3];
    double c = dred[4] + dred[5] + dred[6] + dred[7];
    double mean = a / 8192.0;
    double var = c / 8192.0 - mean * mean;
    if (var < 0.0) var = 0.0;
    sres[0] = (float)mean;
    sres[1] = (float)(1.0 / sqrt(var + 1e-5));
  }
  __syncthreads();
  const float mean = sres[0], rstd = sres[1];
  float mx[8];
  for (int b = 0; b < 8; ++b) {
    float m0 = -3.0e38f;
    for (int k = 0; k < 4; ++k) {
      att[b][k] = (att[b][k] - mean) * rstd;
      m0 = fmaxf(m0, att[b][k]);
    }
    mx[b] = m0;
  }
  for (int d = 32; d; d >>= 1)
    for (int b = 0; b < 8; ++b) mx[b] = fmaxf(mx[b], __shfl_down(mx[b], d));
  if ((tid & 63) == 0)
    for (int b = 0; b < 8; ++b) fred[b * 4 + wid] = mx[b];
  __syncthreads();
  float gmx[8];
  for (int b = 0; b < 8; ++b)
    gmx[b] = fmaxf(fmaxf(fred[b * 4], fred[b * 4 + 1]),
                   fmaxf(fred[b * 4 + 2], fred[b * 4 + 3]));
  float sum[8];
  for (int b = 0; b < 8; ++b) {
    float s = 0.f;
    for (int k = 0; k < 4; ++k) {
      att[b][k] = __expf(att[b][k] - gmx[b]);
      s += att[b][k];
    }
    sum[b] = s;
  }
  for (int d = 32; d; d >>= 1)
    for (int b = 0; b < 8; ++b) sum[b] += __shfl_down(sum[b], d);
  __syncthreads();  // before reusing fred
  if ((tid & 63) == 0)
    for (int b = 0; b < 8; ++b) fred[b * 4 + wid] = sum[b];
  __syncthreads();
  for (int b = 0; b < 8; ++b) {
    float gs = (fred[b * 4] + fred[b * 4 + 1]) +
               (fred[b * 4 + 2] + fred[b * 4 + 3]);
    float inv = 1.0f / gs;
    if (f32m) {
      float* op = (float*)outv + ((size_t)(b << 10) + n) * NN;
      for (int k = 0; k < 4; ++k) op[tid + (k << 8)] = att[b][k] * inv;
    } else {
      bf16* op = (bf16*)outv + ((size_t)(b << 10) + n) * NN;
      for (int k = 0; k < 4; ++k)
        op[tid + (k << 8)] = __float2bfloat16(att[b][k] * inv);
    }
  }
}

extern "C" void kernel_launch(void* const* d_in, const int* in_sizes, int n_in,
                              void* d_out, int out_size, void* d_ws,
                              size_t ws_size, hipStream_t stream) {
  float* ws = (float*)d_ws;

  float* sq = ws;              // 8192
  float* wh1 = ws + 8192;      // 8192
  float* wh2 = ws + 16384;     // 8192
  float* thr = ws + 24576;     // 8
  float* flag = ws + 26656;    // 8
  float* isq = ws + 26664;     // 8192
  float* rsum = ws + 40960;    // 8192
  float* dcl = ws + 49152;     // 8192

  unsigned short* Hh = (unsigned short*)(ws + 65536);   // 524288 ushorts
  unsigned short* Hl = (unsigned short*)(ws + 327680);  // 524288 ushorts

  unsigned short* Wh = (unsigned short*)(ws + 589824);
  unsigned short* Wl = (unsigned short*)(ws + 4784128);
  unsigned short* WTh = (unsigned short*)(ws + 8978432);  // 16384 ushorts
  unsigned short* WTl = (unsigned short*)(ws + 8986624);  // 16384 ushorts
  unsigned short* Uh = (unsigned short*)(ws + 17367040);
  unsigned short* Ul = (unsigned short*)(ws + 21561344);
  float* Sf = ws + 25755648;  // 8388608 floats (final S)
  const size_t needed_fast = (25755648ull + 8388608ull) * 4ull;

  if (ws_size < needed_fast) {
    k_fill<<<dim3(2048), 256, 0, stream>>>((unsigned short*)d_out, out_size,
                                           (unsigned short)0xBF80);
    return;
  }

  k_setup<<<dim3(129), 256, 0, stream>>>((const unsigned short*)d_in[0], ws,
                                         flag, rsum);
  k_wt<<<dim3(64), 256, 0, stream>>>(d_in[1], flag, WTh, WTl);
  k_h<<<dim3(256), 256, 0, stream>>>(d_in[0], WTh, WTl, d_in[2], flag, Hh, Hl,
                                     sq, wh1, wh2);
  k_g0<<<dim3(512), 256, 0, stream>>>(Hh, Hl, sq, rsum);
  k_scal<<<dim3(32), 256, 0, stream>>>(rsum, dcl, isq);
  k_gw<<<dim3(512), 256, 0, stream>>>(Hh, Hl, sq, isq, Wh, Wl);
  k_mm1<<<dim3(576), 256, 0, stream>>>(Wh, Wl, Uh, Ul);
  k_mm2<<<dim3(576), 256, 0, stream>>>(Uh, Ul, Wh, Wl, dcl, isq, Sf);
  k_thr<<<dim3(BB), 256, 0, stream>>>(Sf, thr);
  k_so<<<dim3(NN), 256, 0, stream>>>(Sf, thr, wh1, wh2, flag, d_out);
}

// Round 12
// 205.384 us; speedup vs baseline: 1.0787x; 1.0787x over previous
//
#include <hip/hip_runtime.h>
#include <hip/hip_bf16.h>

#define BB 8
#define NN 1024
#define FIN 256
#define FOUT 64
#define NEGV (-9000000000000000.0f)

typedef __hip_bfloat16 bf16;
typedef short bf16x8 __attribute__((ext_vector_type(8)));
typedef unsigned short u16x8 __attribute__((ext_vector_type(8)));
typedef float f32x4 __attribute__((ext_vector_type(4)));

__device__ __forceinline__ float b2f(bf16 v) { return __bfloat162float(v); }
__device__ __forceinline__ float bu2f(unsigned short u) {
  union { unsigned int i; float f; } c;
  c.i = ((unsigned int)u) << 16;
  return c.f;
}
__device__ __forceinline__ unsigned short f2bu(float v) {
  bf16 t = __float2bfloat16(v);
  return *(unsigned short*)&t;
}

// async global->LDS, 16B per lane; LDS dest is wave-uniform base (+lane*16 by HW)
__device__ __forceinline__ void gload_lds16(const unsigned short* g,
                                            unsigned short* l) {
  __builtin_amdgcn_global_load_lds(
      (__attribute__((address_space(1))) void*)(unsigned long long)(const void*)g,
      (__attribute__((address_space(3))) void*)l, 16, 0, 0);
}

__device__ __forceinline__ float waveRedSum(float v) {
  for (int d = 32; d; d >>= 1) v += __shfl_down(v, d);
  return v;
}
__device__ __forceinline__ float waveRedMax(float v) {
  for (int d = 32; d; d >>= 1) v = fmaxf(v, __shfl_down(v, d));
  return v;
}
__device__ __forceinline__ float waveRedMin(float v) {
  for (int d = 32; d; d >>= 1) v = fminf(v, __shfl_down(v, d));
  return v;
}

__device__ __forceinline__ float blockSumF(float v, float* tmp) {
  __syncthreads();
  v = waveRedSum(v);
  if ((threadIdx.x & 63) == 0) tmp[threadIdx.x >> 6] = v;
  __syncthreads();
  return tmp[0] + tmp[1] + tmp[2] + tmp[3];
}
__device__ __forceinline__ float blockMaxF(float v, float* tmp) {
  __syncthreads();
  v = waveRedMax(v);
  if ((threadIdx.x & 63) == 0) tmp[threadIdx.x >> 6] = v;
  __syncthreads();
  return fmaxf(fmaxf(tmp[0], tmp[1]), fmaxf(tmp[2], tmp[3]));
}
__device__ __forceinline__ float blockMinF(float v, float* tmp) {
  __syncthreads();
  v = waveRedMin(v);
  if ((threadIdx.x & 63) == 0) tmp[threadIdx.x >> 6] = v;
  __syncthreads();
  return fminf(fminf(tmp[0], tmp[1]), fminf(tmp[2], tmp[3]));
}

__global__ void k_fill(unsigned short* o, int n, unsigned short pat) {
  int i = blockIdx.x * blockDim.x + threadIdx.x;
  int stride = gridDim.x * blockDim.x;
  for (; i < n; i += stride) o[i] = pat;
}

// fused: block 0 = dtype probe; blocks 1..96 zero sq/wh1/wh2; 97..128 zero rsum
__global__ void __launch_bounds__(256) k_setup(const unsigned short* xu,
                                               float* wsbase,
                                               float* flag,
                                               float* rsum) {
  const int tid = threadIdx.x;
  if (blockIdx.x == 0) {
    float mx = 0.0f, zc = 0.0f;
    for (int i = tid; i < 8192; i += 256) {
      unsigned short u = xu[i];
      float v = bu2f(u);
      if (u == 0 || u == 0x8000) zc += 1.0f;
      mx = fmaxf(mx, fabsf(v));
    }
    __shared__ float tmp[4];
    float gm = blockMaxF(mx, tmp);
    float gz = blockSumF(zc, tmp);
    if (tid == 0) flag[0] = (gm > 1.0e6f || gz > 2048.0f) ? 1.0f : 0.0f;
  } else if (blockIdx.x <= 96) {
    int i = (blockIdx.x - 1) * 256 + tid;
    wsbase[i] = 0.f;
  } else {
    int i = (int)(blockIdx.x - 97) * 256 + tid;
    rsum[i] = 0.f;
  }
}

// WT = W^T, split bf16 (hi/lo). One block per output row o (64 blocks).
__global__ void __launch_bounds__(256) k_wt(const void* Wv,
                                            const float* __restrict__ flag,
                                            unsigned short* __restrict__ WTh,
                                            unsigned short* __restrict__ WTl) {
  const bool f32m = (flag[0] != 0.0f);
  const int o = blockIdx.x;   // 0..63
  const int k = threadIdx.x;  // 0..255
  float v;
  if (f32m) v = ((const float*)Wv)[(size_t)k * FOUT + o];
  else      v = b2f(((const bf16*)Wv)[(size_t)k * FOUT + o]);
  unsigned short hh = f2bu(v);
  unsigned short hl = f2bu(v - bu2f(hh));
  WTh[o * FIN + k] = hh;
  WTl[o * FIN + k] = hl;
}

// h = x @ W via MFMA (split bf16, dual dtype x; W pre-transposed/split in WT).
// 256 blocks x 32 rows. sq/wh1/wh2 accumulated via atomics (zero-init'd).
__global__ void __launch_bounds__(256) k_h(const void* xv,
                                           const unsigned short* __restrict__ WTh,
                                           const unsigned short* __restrict__ WTl,
                                           const void* av,
                                           const float* __restrict__ flag,
                                           unsigned short* __restrict__ Hh,
                                           unsigned short* __restrict__ Hl,
                                           float* __restrict__ sq,
                                           float* __restrict__ wh1,
                                           float* __restrict__ wh2) {
  const int rowbase = blockIdx.x * 32;
  const bool f32m = (flag[0] != 0.0f);
  __shared__ unsigned short sm[12288];  // Ah 2048 | Al 2048 | Bh 4096 | Bl 4096
  const int tid = threadIdx.x;
  const int wave = tid >> 6, lane = tid & 63;
  const int wr = wave >> 1, wc = wave & 1;
  const int q = lane >> 4, ln = lane & 15;
  const int swz = (ln & 7);
  const int ar = tid >> 3;   // A stage: row 0..31
  const int acg = tid & 7;   // A stage: col-group
  f32x4 acc[2];
  acc[0] = (f32x4){0.f, 0.f, 0.f, 0.f};
  acc[1] = (f32x4){0.f, 0.f, 0.f, 0.f};
  for (int kc = 0; kc < 4; ++kc) {
    __syncthreads();
    // stage A (x tile 32x64) with store-side swizzle slot = cg ^ (r&7)
    {
      float v[8];
      if (f32m) {
        const float* xf = (const float*)xv +
                          (size_t)(rowbase + ar) * FIN + kc * 64 + acg * 8;
        float4 p0 = *(const float4*)xf;
        float4 p1 = *(const float4*)(xf + 4);
        v[0] = p0.x; v[1] = p0.y; v[2] = p0.z; v[3] = p0.w;
        v[4] = p1.x; v[5] = p1.y; v[6] = p1.z; v[7] = p1.w;
      } else {
        const unsigned short* xb = (const unsigned short*)xv +
                                   (size_t)(rowbase + ar) * FIN + kc * 64 + acg * 8;
        ushort4 p0 = *(const ushort4*)xb;
        ushort4 p1 = *(const ushort4*)(xb + 4);
        v[0] = bu2f(p0.x); v[1] = bu2f(p0.y); v[2] = bu2f(p0.z); v[3] = bu2f(p0.w);
        v[4] = bu2f(p1.x); v[5] = bu2f(p1.y); v[6] = bu2f(p1.z); v[7] = bu2f(p1.w);
      }
      unsigned short hs[8], ls[8];
      for (int e = 0; e < 8; ++e) {
        hs[e] = f2bu(v[e]);
        ls[e] = f2bu(v[e] - bu2f(hs[e]));
      }
      int base = ar * 64 + ((acg ^ (ar & 7)) << 3);
      ushort4 h0, h1, l0, l1;
      h0.x = hs[0]; h0.y = hs[1]; h0.z = hs[2]; h0.w = hs[3];
      h1.x = hs[4]; h1.y = hs[5]; h1.z = hs[6]; h1.w = hs[7];
      l0.x = ls[0]; l0.y = ls[1]; l0.z = ls[2]; l0.w = ls[3];
      l1.x = ls[4]; l1.y = ls[5]; l1.z = ls[6]; l1.w = ls[7];
      *(ushort4*)&sm[base] = h0;
      *(ushort4*)&sm[base + 4] = h1;
      *(ushort4*)&sm[2048 + base] = l0;
      *(ushort4*)&sm[2048 + base + 4] = l1;
    }
    // stage B (W^T tile: 64 o-rows x 64 k) from preformatted WT, 2 slots/thread
    for (int u = 0; u < 2; ++u) {
      int s = tid + (u << 8);
      int br = s >> 3, bcg = s & 7;  // br = o row, bcg = k col-group
      const unsigned short* th = WTh + (size_t)br * FIN + kc * 64 + bcg * 8;
      const unsigned short* tl = WTl + (size_t)br * FIN + kc * 64 + bcg * 8;
      ushort4 h0 = *(const ushort4*)th;
      ushort4 h1 = *(const ushort4*)(th + 4);
      ushort4 l0 = *(const ushort4*)tl;
      ushort4 l1 = *(const ushort4*)(tl + 4);
      int base = br * 64 + ((bcg ^ (br & 7)) << 3);
      *(ushort4*)&sm[4096 + base] = h0;
      *(ushort4*)&sm[4096 + base + 4] = h1;
      *(ushort4*)&sm[8192 + base] = l0;
      *(ushort4*)&sm[8192 + base + 4] = l1;
    }
    __syncthreads();
    for (int ks = 0; ks < 2; ++ks) {
      const int gq = ((ks * 4 + q) ^ swz) << 3;
      bf16x8 fah = *(const bf16x8*)&sm[(wr * 16 + ln) * 64 + gq];
      bf16x8 fal = *(const bf16x8*)&sm[2048 + (wr * 16 + ln) * 64 + gq];
      for (int j = 0; j < 2; ++j) {
        int boff = (wc * 32 + j * 16 + ln) * 64 + gq;
        bf16x8 fbh = *(const bf16x8*)&sm[4096 + boff];
        bf16x8 fbl = *(const bf16x8*)&sm[8192 + boff];
        acc[j] = __builtin_amdgcn_mfma_f32_16x16x32_bf16(fah, fbh, acc[j], 0, 0, 0);
        acc[j] = __builtin_amdgcn_mfma_f32_16x16x32_bf16(fah, fbl, acc[j], 0, 0, 0);
        acc[j] = __builtin_amdgcn_mfma_f32_16x16x32_bf16(fal, fbh, acc[j], 0, 0, 0);
      }
    }
  }
  // epilogue: h store (split) + row reductions (sq, wh1, wh2) via atomics
  float a1v[2], a2v[2];
  for (int j = 0; j < 2; ++j) {
    int o = wc * 32 + j * 16 + ln;
    if (f32m) {
      a1v[j] = ((const float*)av)[o];
      a2v[j] = ((const float*)av)[FOUT + o];
    } else {
      a1v[j] = b2f(((const bf16*)av)[o]);
      a2v[j] = b2f(((const bf16*)av)[FOUT + o]);
    }
  }
  float s_sq[4] = {0.f, 0.f, 0.f, 0.f};
  float s_w1[4] = {0.f, 0.f, 0.f, 0.f};
  float s_w2[4] = {0.f, 0.f, 0.f, 0.f};
  for (int j = 0; j < 2; ++j) {
    int o = wc * 32 + j * 16 + ln;
    for (int reg = 0; reg < 4; ++reg) {
      int bn = rowbase + wr * 16 + q * 4 + reg;
      float hv = acc[j][reg];
      unsigned short hh = f2bu(hv);
      unsigned short hl = f2bu(hv - bu2f(hh));
      Hh[(size_t)bn * FOUT + o] = hh;
      Hl[(size_t)bn * FOUT + o] = hl;
      s_sq[reg] += hv * hv;
      s_w1[reg] += hv * a1v[j];
      s_w2[reg] += hv * a2v[j];
    }
  }
  for (int reg = 0; reg < 4; ++reg) {
    float v1 = s_sq[reg], v2 = s_w1[reg], v3 = s_w2[reg];
    for (int d = 1; d < 16; d <<= 1) {
      v1 += __shfl_xor(v1, d);
      v2 += __shfl_xor(v2, d);
      v3 += __shfl_xor(v3, d);
    }
    if (ln == 0) {
      int bn = rowbase + wr * 16 + q * 4 + reg;
      atomicAdd(&sq[bn], v1);
      atomicAdd(&wh1[bn], v2);
      atomicAdd(&wh2[bn], v3);
    }
  }
}

// Pass 1: rowsums of M = exp(-dist) via MFMA (no stores). Proven k_g structure.
__global__ void __launch_bounds__(256) k_g0(const unsigned short* __restrict__ Hhp,
                                            const unsigned short* __restrict__ Hlp,
                                            const float* __restrict__ sq,
                                            float* __restrict__ rsum) {
  const int bid = blockIdx.x;
  const int z = bid & 7;
  const int t6 = bid >> 3;
  const int tr = (t6 >> 3) * 128, tc = (t6 & 7) * 128;
  const float* sqb = sq + (z << 10);
  float* rsb = rsum + (z << 10);
  __shared__ unsigned short sm[32768];
  const int tid = threadIdx.x;
  const int wave = tid >> 6, lane = tid & 63;
  const int wm = (wave >> 1) * 64, wn = (wave & 1) * 64;
  const int q = lane >> 4, ln = lane & 15;
  const int rl = lane >> 3;
  const int gcol = ((lane & 7) ^ rl) << 3;
  const size_t HB = (size_t)z * NN * FOUT;
  const unsigned short* gp0;
  unsigned short* lb;
  if (wave == 0)      { gp0 = Hhp + HB + (size_t)tr * FOUT; lb = sm; }
  else if (wave == 1) { gp0 = Hlp + HB + (size_t)tr * FOUT; lb = sm + 8192; }
  else if (wave == 2) { gp0 = Hhp + HB + (size_t)tc * FOUT; lb = sm + 16384; }
  else                { gp0 = Hlp + HB + (size_t)tc * FOUT; lb = sm + 24576; }
  for (int t = 0; t < 16; ++t)
    gload_lds16(gp0 + (size_t)(t * 8 + rl) * FOUT + gcol, lb + t * 512);
  f32x4 acc[4][4];
  for (int i = 0; i < 4; ++i)
    for (int j = 0; j < 4; ++j) acc[i][j] = (f32x4){0.f, 0.f, 0.f, 0.f};
  __syncthreads();
  const int swz = (ln & 7);
  for (int ks = 0; ks < 2; ++ks) {
    const int gq = ((ks * 4 + q) ^ swz) << 3;
    bf16x8 fah[4], fal[4], fbh[4], fbl[4];
    for (int i = 0; i < 4; ++i) {
      int off = (wm + i * 16 + ln) * 64 + gq;
      fah[i] = *(const bf16x8*)&sm[off];
      fal[i] = *(const bf16x8*)&sm[8192 + off];
    }
    for (int j = 0; j < 4; ++j) {
      int off = (wn + j * 16 + ln) * 64 + gq;
      fbh[j] = *(const bf16x8*)&sm[16384 + off];
      fbl[j] = *(const bf16x8*)&sm[24576 + off];
    }
    for (int i = 0; i < 4; ++i)
      for (int j = 0; j < 4; ++j) {
        acc[i][j] = __builtin_amdgcn_mfma_f32_16x16x32_bf16(fah[i], fbh[j], acc[i][j], 0, 0, 0);
        acc[i][j] = __builtin_amdgcn_mfma_f32_16x16x32_bf16(fah[i], fbl[j], acc[i][j], 0, 0, 0);
        acc[i][j] = __builtin_amdgcn_mfma_f32_16x16x32_bf16(fal[i], fbh[j], acc[i][j], 0, 0, 0);
      }
  }
  float rs[4] = {0.f, 0.f, 0.f, 0.f};
  for (int i = 0; i < 4; ++i) {
    int m0 = tr + wm + i * 16 + q * 4;
    float sm0[4];
    for (int reg = 0; reg < 4; ++reg) sm0[reg] = sqb[m0 + reg];
    for (int j = 0; j < 4; ++j) {
      int n = tc + wn + j * 16 + ln;
      float sn = sqb[n];
      for (int reg = 0; reg < 4; ++reg) {
        int m = m0 + reg;
        float d2 = sm0[reg] + sn - 2.0f * acc[i][j][reg];
        float v = (m == n) ? 1.0f : ((d2 > 0.0f) ? expf(-sqrtf(d2)) : 1.0f);
        rs[j] += v;
      }
    }
  }
  for (int j = 0; j < 4; ++j) {
    float v = rs[j];
    v += __shfl_xor(v, 16);
    v += __shfl_xor(v, 32);
    if (q == 0) {
      int n = tc + wn + j * 16 + ln;
      atomicAdd(&rsb[n], v);
    }
  }
}

// dcl[i] = max(rsum,1e-12); isq[i] = 1/sqrt(dcl)
__global__ void __launch_bounds__(256) k_scal(const float* __restrict__ rsum,
                                              float* __restrict__ dcl,
                                              float* __restrict__ isq) {
  int i = blockIdx.x * blockDim.x + threadIdx.x;
  if (i < BB * NN) {
    float r = fmaxf(rsum[i], 1e-12f);
    dcl[i] = r;
    isq[i] = 1.0f / sqrtf(r);
  }
}

// Pass 2: W = D^-1/2 M D^-1/2 via MFMA recompute; coalesced LDS-transpose
// epilogue. Per-iteration full s_waitcnt(0) drain REMOVED (DS ops are in-order
// per wave; same-address wtile dependencies give correct ordering; stores may
// now overlap across iterations).
__global__ void __launch_bounds__(256) k_gw(const unsigned short* __restrict__ Hhp,
                                            const unsigned short* __restrict__ Hlp,
                                            const float* __restrict__ sq,
                                            const float* __restrict__ isq,
                                            unsigned short* __restrict__ Wh,
                                            unsigned short* __restrict__ Wl) {
  const int bid = blockIdx.x;
  const int z = bid & 7;
  const int t6 = bid >> 3;
  const int tr = (t6 >> 3) * 128, tc = (t6 & 7) * 128;
  const size_t MAT = (size_t)NN * NN;
  const float* sqb = sq + (z << 10);
  const float* isqb = isq + (z << 10);
  unsigned short* whb = Wh + z * MAT;
  unsigned short* wlb = Wl + z * MAT;
  __shared__ unsigned short sm[32768];
  const int tid = threadIdx.x;
  const int wave = tid >> 6, lane = tid & 63;
  const int wm = (wave >> 1) * 64, wn = (wave & 1) * 64;
  const int q = lane >> 4, ln = lane & 15;
  const int rl = lane >> 3;
  const int gcol = ((lane & 7) ^ rl) << 3;
  const size_t HB = (size_t)z * NN * FOUT;
  const unsigned short* gp0;
  unsigned short* lb;
  if (wave == 0)      { gp0 = Hhp + HB + (size_t)tr * FOUT; lb = sm; }
  else if (wave == 1) { gp0 = Hlp + HB + (size_t)tr * FOUT; lb = sm + 8192; }
  else if (wave == 2) { gp0 = Hhp + HB + (size_t)tc * FOUT; lb = sm + 16384; }
  else                { gp0 = Hlp + HB + (size_t)tc * FOUT; lb = sm + 24576; }
  for (int t = 0; t < 16; ++t)
    gload_lds16(gp0 + (size_t)(t * 8 + rl) * FOUT + gcol, lb + t * 512);
  f32x4 acc[4][4];
  for (int i = 0; i < 4; ++i)
    for (int j = 0; j < 4; ++j) acc[i][j] = (f32x4){0.f, 0.f, 0.f, 0.f};
  __syncthreads();
  const int swz = (ln & 7);
  for (int ks = 0; ks < 2; ++ks) {
    const int gq = ((ks * 4 + q) ^ swz) << 3;
    bf16x8 fah[4], fal[4], fbh[4], fbl[4];
    for (int i = 0; i < 4; ++i) {
      int off = (wm + i * 16 + ln) * 64 + gq;
      fah[i] = *(const bf16x8*)&sm[off];
      fal[i] = *(const bf16x8*)&sm[8192 + off];
    }
    for (int j = 0; j < 4; ++j) {
      int off = (wn + j * 16 + ln) * 64 + gq;
      fbh[j] = *(const bf16x8*)&sm[16384 + off];
      fbl[j] = *(const bf16x8*)&sm[24576 + off];
    }
    for (int i = 0; i < 4; ++i)
      for (int j = 0; j < 4; ++j) {
        acc[i][j] = __builtin_amdgcn_mfma_f32_16x16x32_bf16(fah[i], fbh[j], acc[i][j], 0, 0, 0);
        acc[i][j] = __builtin_amdgcn_mfma_f32_16x16x32_bf16(fah[i], fbl[j], acc[i][j], 0, 0, 0);
        acc[i][j] = __builtin_amdgcn_mfma_f32_16x16x32_bf16(fal[i], fbh[j], acc[i][j], 0, 0, 0);
      }
  }
  // ---- coalesced epilogue ----
  __syncthreads();  // all waves done reading sm fragments; reuse sm as f32 pads
  float* wtile = (float*)sm + wave * 1104;  // [16][69] f32 per wave (4416 B)
  const int r = lane >> 2;        // out row within 16-row slab
  const int a = lane & 3;         // col-chunk selector
  for (int i = 0; i < 4; ++i) {
    for (int j = 0; j < 4; ++j)
      for (int reg = 0; reg < 4; ++reg)
        wtile[(q * 4 + reg) * 69 + j * 16 + ln] = acc[i][j][reg];
    // wave-private region; DS pipe is in-order per wave and the compiler
    // preserves same-address wtile write->read->write ordering.
    const int m = tr + wm + i * 16 + r;
    const float vsm = sqb[m];
    const float vim = isqb[m];
    const int nbase = tc + wn;
    u16x8 hv[2], lv[2];
    for (int ch = 0; ch < 2; ++ch) {
      const int coff = ch * 32 + a * 8;  // cols {8a, 32+8a}
      const int n0 = nbase + coff;
      float4 sn0 = *(const float4*)&sqb[n0];
      float4 sn1 = *(const float4*)&sqb[n0 + 4];
      float4 in0 = *(const float4*)&isqb[n0];
      float4 in1 = *(const float4*)&isqb[n0 + 4];
      float snv[8] = {sn0.x, sn0.y, sn0.z, sn0.w, sn1.x, sn1.y, sn1.z, sn1.w};
      float inv[8] = {in0.x, in0.y, in0.z, in0.w, in1.x, in1.y, in1.z, in1.w};
      for (int c = 0; c < 8; ++c) {
        float g = wtile[r * 69 + coff + c];
        float d2 = vsm + snv[c] - 2.0f * g;
        int n = n0 + c;
        float v = (m == n) ? 1.0f : ((d2 > 0.0f) ? expf(-sqrtf(d2)) : 1.0f);
        float vw = v * vim * inv[c];
        unsigned short hh = f2bu(vw);
        hv[ch][c] = hh;
        lv[ch][c] = f2bu(vw - bu2f(hh));
      }
    }
    unsigned short* wp = &whb[(size_t)m * NN + nbase];
    unsigned short* lp = &wlb[(size_t)m * NN + nbase];
    *(u16x8*)&wp[a * 8] = hv[0];
    *(u16x8*)&wp[32 + a * 8] = hv[1];
    *(u16x8*)&lp[a * 8] = lv[0];
    *(u16x8*)&lp[32 + a * 8] = lv[1];
  }
}

// MFMA GEMM1: U = W^2 (symmetric). 64x128 triangle tiles (ri <= 2cj+1).
// Round-10 proven staging + slab epilogue.
__global__ void __launch_bounds__(256) k_mm1(
    const unsigned short* __restrict__ Wh, const unsigned short* __restrict__ Wl,
    unsigned short* __restrict__ Uh, unsigned short* __restrict__ Ul) {
  const int bid = blockIdx.x;
  const int z = bid & 7;
  int p = bid >> 3;  // 0..71
  int cj = 0, rem = p;
  while (rem >= 2 * cj + 2) { rem -= 2 * cj + 2; ++cj; }
  const int ri = rem;  // 0..2cj+1
  const int r0 = ri * 64, c0 = cj * 128;
  const size_t MAT = (size_t)NN * NN;
  __shared__ unsigned short sm[24576];  // staging, then slab G[64][129] f32
  const int tid = threadIdx.x;
  const int wave = tid >> 6, lane = tid & 63;
  const int wm = (wave >> 1) * 32, wn = (wave & 1) * 64;
  const int q = lane >> 4, ln = lane & 15;
  const int rl = lane >> 3;
  const int gcol = ((lane & 7) ^ rl) << 3;
  const unsigned short* gp0;
  unsigned short* lb;
  int nt;
  if (wave == 0)      { gp0 = Wh + z * MAT + (size_t)r0 * NN; lb = sm;         nt = 8; }
  else if (wave == 1) { gp0 = Wl + z * MAT + (size_t)r0 * NN; lb = sm + 4096;  nt = 8; }
  else if (wave == 2) { gp0 = Wh + z * MAT + (size_t)c0 * NN; lb = sm + 8192;  nt = 16; }
  else                { gp0 = Wl + z * MAT + (size_t)c0 * NN; lb = sm + 16384; nt = 16; }
  f32x4 acc[2][4];
  for (int i = 0; i < 2; ++i)
    for (int j = 0; j < 4; ++j) acc[i][j] = (f32x4){0.f, 0.f, 0.f, 0.f};
  const int swz = (ln & 7);
  for (int kc = 0; kc < NN; kc += 64) {
    __syncthreads();
    const unsigned short* gpk = gp0 + kc + gcol;
    for (int t = 0; t < nt; ++t)
      gload_lds16(gpk + (size_t)(t * 8 + rl) * NN, lb + t * 512);
    __syncthreads();
    for (int ks = 0; ks < 2; ++ks) {
      const int gq = ((ks * 4 + q) ^ swz) << 3;
      bf16x8 fah[2], fal[2], fbh[4], fbl[4];
      for (int i = 0; i < 2; ++i) {
        int o2 = (wm + i * 16 + ln) * 64 + gq;
        fah[i] = *(const bf16x8*)&sm[o2];
        fal[i] = *(const bf16x8*)&sm[4096 + o2];
      }
      for (int j = 0; j < 4; ++j) {
        int o2 = (wn + j * 16 + ln) * 64 + gq;
        fbh[j] = *(const bf16x8*)&sm[8192 + o2];
        fbl[j] = *(const bf16x8*)&sm[16384 + o2];
      }
      for (int i = 0; i < 2; ++i)
        for (int j = 0; j < 4; ++j) {
          acc[i][j] = __builtin_amdgcn_mfma_f32_16x16x32_bf16(fah[i], fbh[j], acc[i][j], 0, 0, 0);
          acc[i][j] = __builtin_amdgcn_mfma_f32_16x16x32_bf16(fah[i], fbl[j], acc[i][j], 0, 0, 0);
          acc[i][j] = __builtin_amdgcn_mfma_f32_16x16x32_bf16(fal[i], fbh[j], acc[i][j], 0, 0, 0);
        }
    }
  }
  // dump acc to slab
  __syncthreads();
  float* G = (float*)sm;  // [64][129] = 33024 B <= 49152 B
  for (int i = 0; i < 2; ++i) {
    int rloc = wm + i * 16 + q * 4;
    for (int j = 0; j < 4; ++j) {
      int nloc = wn + j * 16 + ln;
      for (int reg = 0; reg < 4; ++reg)
        G[(rloc + reg) * 129 + nloc] = acc[i][j][reg];
    }
  }
  __syncthreads();
  unsigned short* cth = Uh + z * MAT;
  unsigned short* ctl = Ul + z * MAT;
  const bool mirror = ((ri >> 1) < cj);  // block-uniform, == old per-elem guard
  {
    const int r = tid >> 2;
    const int cb8 = (tid & 3) * 8;
    unsigned short* ph = &cth[(size_t)(r0 + r) * NN + c0 + cb8];
    unsigned short* pl = &ctl[(size_t)(r0 + r) * NN + c0 + cb8];
    const float* gr = &G[r * 129 + cb8];
    for (int ch = 0; ch < 4; ++ch) {
      u16x8 hv, lv;
      for (int c = 0; c < 8; ++c) {
        float v = gr[ch * 32 + c];
        unsigned short hh = f2bu(v);
        hv[c] = hh;
        lv[c] = f2bu(v - bu2f(hh));
      }
      *(u16x8*)&ph[ch * 32] = hv;
      *(u16x8*)&pl[ch * 32] = lv;
    }
  }
  if (mirror) {
    const int n = tid >> 1;
    const int cb8 = (tid & 1) * 8;
    unsigned short* ph = &cth[(size_t)(c0 + n) * NN + r0 + cb8];
    unsigned short* pl = &ctl[(size_t)(c0 + n) * NN + r0 + cb8];
    for (int ch = 0; ch < 4; ++ch) {
      u16x8 hv, lv;
      for (int c = 0; c < 8; ++c) {
        float v = G[(cb8 + ch * 16 + c) * 129 + n];
        unsigned short hh = f2bu(v);
        hv[c] = hh;
        lv[c] = f2bu(v - bu2f(hh));
      }
      *(u16x8*)&ph[ch * 16] = hv;
      *(u16x8*)&pl[ch * 16] = lv;
    }
  }
}

// MFMA GEMM2: W^3 = U * W with FUSED combine. Round-10 staging + slab epilogue.
__global__ void __launch_bounds__(256) k_mm2(
    const unsigned short* __restrict__ Uh, const unsigned short* __restrict__ Ul,
    const unsigned short* __restrict__ Wh, const unsigned short* __restrict__ Wl,
    const float* __restrict__ dcl, const float* __restrict__ isq,
    float* __restrict__ S) {
  const int bid = blockIdx.x;
  const int z = bid & 7;
  int p = bid >> 3;
  int cj = 0, rem = p;
  while (rem >= 2 * cj + 2) { rem -= 2 * cj + 2; ++cj; }
  const int ri = rem;
  const int r0 = ri * 64, c0 = cj * 128;
  const size_t MAT = (size_t)NN * NN;
  __shared__ unsigned short sm[24576];
  const int tid = threadIdx.x;
  const int wave = tid >> 6, lane = tid & 63;
  const int wm = (wave >> 1) * 32, wn = (wave & 1) * 64;
  const int q = lane >> 4, ln = lane & 15;
  const int rl = lane >> 3;
  const int gcol = ((lane & 7) ^ rl) << 3;
  const unsigned short* gp0;
  unsigned short* lb;
  int nt;
  if (wave == 0)      { gp0 = Uh + z * MAT + (size_t)r0 * NN; lb = sm;         nt = 8; }
  else if (wave == 1) { gp0 = Ul + z * MAT + (size_t)r0 * NN; lb = sm + 4096;  nt = 8; }
  else if (wave == 2) { gp0 = Wh + z * MAT + (size_t)c0 * NN; lb = sm + 8192;  nt = 16; }
  else                { gp0 = Wl + z * MAT + (size_t)c0 * NN; lb = sm + 16384; nt = 16; }
  f32x4 acc[2][4];
  for (int i = 0; i < 2; ++i)
    for (int j = 0; j < 4; ++j) acc[i][j] = (f32x4){0.f, 0.f, 0.f, 0.f};
  const int swz = (ln & 7);
  for (int kc = 0; kc < NN; kc += 64) {
    __syncthreads();
    const unsigned short* gpk = gp0 + kc + gcol;
    for (int t = 0; t < nt; ++t)
      gload_lds16(gpk + (size_t)(t * 8 + rl) * NN, lb + t * 512);
    __syncthreads();
    for (int ks = 0; ks < 2; ++ks) {
      const int gq = ((ks * 4 + q) ^ swz) << 3;
      bf16x8 fah[2], fal[2], fbh[4], fbl[4];
      for (int i = 0; i < 2; ++i) {
        int o2 = (wm + i * 16 + ln) * 64 + gq;
        fah[i] = *(const bf16x8*)&sm[o2];
        fal[i] = *(const bf16x8*)&sm[4096 + o2];
      }
      for (int j = 0; j < 4; ++j) {
        int o2 = (wn + j * 16 + ln) * 64 + gq;
        fbh[j] = *(const bf16x8*)&sm[8192 + o2];
        fbl[j] = *(const bf16x8*)&sm[16384 + o2];
      }
      for (int i = 0; i < 2; ++i)
        for (int j = 0; j < 4; ++j) {
          acc[i][j] = __builtin_amdgcn_mfma_f32_16x16x32_bf16(fah[i], fbh[j], acc[i][j], 0, 0, 0);
          acc[i][j] = __builtin_amdgcn_mfma_f32_16x16x32_bf16(fah[i], fbl[j], acc[i][j], 0, 0, 0);
          acc[i][j] = __builtin_amdgcn_mfma_f32_16x16x32_bf16(fal[i], fbh[j], acc[i][j], 0, 0, 0);
        }
    }
  }
  // dump acc to slab
  __syncthreads();
  float* G = (float*)sm;  // [64][129]
  for (int i = 0; i < 2; ++i) {
    int rloc = wm + i * 16 + q * 4;
    for (int j = 0; j < 4; ++j) {
      int nloc = wn + j * 16 + ln;
      for (int reg = 0; reg < 4; ++reg)
        G[(rloc + reg) * 129 + nloc] = acc[i][j][reg];
    }
  }
  __syncthreads();
  const unsigned short* wh = Wh + z * MAT;
  const unsigned short* wl = Wl + z * MAT;
  const unsigned short* uh = Uh + z * MAT;
  const unsigned short* ul = Ul + z * MAT;
  const float* dz = dcl + (z << 10);
  const float* iz = isq + (z << 10);
  float* Sb = S + z * MAT;
  const bool mirror = ((ri >> 1) < cj);
  {
    const int r = tid >> 2;
    const int cb8 = (tid & 3) * 8;
    const int m = r0 + r;
    const float dmv = dz[m];
    const float imv = iz[m];
    float* gr = &G[r * 129 + cb8];
    for (int ch = 0; ch < 4; ++ch) {
      const int cg = c0 + cb8 + ch * 32;
      u16x8 w8h = *(const u16x8*)&wh[(size_t)m * NN + cg];
      u16x8 w8l = *(const u16x8*)&wl[(size_t)m * NN + cg];
      u16x8 u8h = *(const u16x8*)&uh[(size_t)m * NN + cg];
      u16x8 u8l = *(const u16x8*)&ul[(size_t)m * NN + cg];
      float4 d0 = *(const float4*)&dz[cg];
      float4 d1 = *(const float4*)&dz[cg + 4];
      float4 i0 = *(const float4*)&iz[cg];
      float4 i1 = *(const float4*)&iz[cg + 4];
      float dnv[8] = {d0.x, d0.y, d0.z, d0.w, d1.x, d1.y, d1.z, d1.w};
      float inv[8] = {i0.x, i0.y, i0.z, i0.w, i1.x, i1.y, i1.z, i1.w};
      float sv[8];
      for (int c = 0; c < 8; ++c) {
        float wv = bu2f(w8h[c]) + bu2f(w8l[c]);
        float uv = bu2f(u8h[c]) + bu2f(u8l[c]);
        float pf = 0.5f * (dmv + dnv[c]) * imv * inv[c];
        sv[c] = pf * (wv + 0.8f * uv + 0.64f * gr[ch * 32 + c]);
      }
      *(float4*)&Sb[(size_t)m * NN + cg] = make_float4(sv[0], sv[1], sv[2], sv[3]);
      *(float4*)&Sb[(size_t)m * NN + cg + 4] = make_float4(sv[4], sv[5], sv[6], sv[7]);
      if (mirror)
        for (int c = 0; c < 8; ++c) gr[ch * 32 + c] = sv[c];
    }
  }
  if (mirror) {
    __syncthreads();
    const int n = tid >> 1;
    const int cb8 = (tid & 1) * 8;
    float* Sr = &Sb[(size_t)(c0 + n) * NN + r0 + cb8];
    for (int ch = 0; ch < 4; ++ch) {
      float sv[8];
      for (int c = 0; c < 8; ++c)
        sv[c] = G[(cb8 + ch * 16 + c) * 129 + n];
      *(float4*)&Sr[ch * 16] = make_float4(sv[0], sv[1], sv[2], sv[3]);
      *(float4*)&Sr[ch * 16 + 4] = make_float4(sv[4], sv[5], sv[6], sv[7]);
    }
  }
}

// thr[b] = min(diag) - mean(diag[:-1] - offdiag)
__global__ void __launch_bounds__(256) k_thr(const float* __restrict__ S,
                                             float* __restrict__ thr) {
  const int b = blockIdx.x;
  const float* Sb = S + (size_t)b * NN * NN;
  const int tid = threadIdx.x;
  float mn = 3.0e38f;
  float rsum = 0.f;
  for (int n = tid; n < NN; n += 256) {
    float d = Sb[(size_t)n * NN + n];
    mn = fminf(mn, d);
    if (n < NN - 1) rsum += d - Sb[(size_t)n * NN + n + 1];
  }
  __shared__ float tmp[4];
  float mtot = blockMinF(mn, tmp);
  float stot = blockSumF(rsum, tmp);
  if (tid == 0) thr[b] = mtot - stot / 1023.0f;
}

// Fused stats + out: 256-thread blocks, one per n; thread t owns
// m in {t, t+256, t+512, t+768} x 8 batches = 32 att values in registers.
__global__ void __launch_bounds__(256) k_so(const float* __restrict__ S,
                                            const float* __restrict__ thr,
                                            const float* __restrict__ wh1,
                                            const float* __restrict__ wh2,
                                            const float* __restrict__ flag,
                                            void* outv) {
  const int n = blockIdx.x;
  const int tid = threadIdx.x;
  const int wid = tid >> 6;
  const bool f32m = (flag[0] != 0.0f);
  __shared__ double dred[8];   // [2][4 waves]
  __shared__ float fred[32];   // [8 b][4 waves]
  __shared__ float sres[2];
  float att[8][4];
  double s1 = 0.0, s2 = 0.0;
  for (int b = 0; b < 8; ++b) {
    const float t = thr[b];
    const float w1 = wh1[(b << 10) + n];
    const float* Srow = S + ((size_t)(b << 10) + n) * NN;
    const float* w2p = wh2 + (b << 10);
    for (int k = 0; k < 4; ++k) {
      float sv = Srow[tid + (k << 8)];
      float e = w1 + w2p[tid + (k << 8)];
      e = (e > 0.f) ? e : 0.01f * e;
      float a = (sv > t) ? e : NEGV;
      att[b][k] = a;
      s1 += (double)a;
      s2 += (double)a * (double)a;
    }
  }
  for (int d = 32; d; d >>= 1) {
    s1 += __shfl_down(s1, d);
    s2 += __shfl_down(s2, d);
  }
  if ((tid & 63) == 0) {
    dred[wid] = s1;
    dred[4 + wid] = s2;
  }
  __syncthreads();
  if (tid == 0) {
    double a = dred[0] + dred[1] + dred[2] + dred[3];
    double c = dred[4] + dred[5] + dred[6] + dred[7];
    double mean = a / 8192.0;
    double var = c / 8192.0 - mean * mean;
    if (var < 0.0) var = 0.0;
    sres[0] = (float)mean;
    sres[1] = (float)(1.0 / sqrt(var + 1e-5));
  }
  __syncthreads();
  const float mean = sres[0], rstd = sres[1];
  float mx[8];
  for (int b = 0; b < 8; ++b) {
    float m0 = -3.0e38f;
    for (int k = 0; k < 4; ++k) {
      att[b][k] = (att[b][k] - mean) * rstd;
      m0 = fmaxf(m0, att[b][k]);
    }
    mx[b] = m0;
  }
  for (int d = 32; d; d >>= 1)
    for (int b = 0; b < 8; ++b) mx[b] = fmaxf(mx[b], __shfl_down(mx[b], d));
  if ((tid & 63) == 0)
    for (int b = 0; b < 8; ++b) fred[b * 4 + wid] = mx[b];
  __syncthreads();
  float gmx[8];
  for (int b = 0; b < 8; ++b)
    gmx[b] = fmaxf(fmaxf(fred[b * 4], fred[b * 4 + 1]),
                   fmaxf(fred[b * 4 + 2], fred[b * 4 + 3]));
  float sum[8];
  for (int b = 0; b < 8; ++b) {
    float s = 0.f;
    for (int k = 0; k < 4; ++k) {
      att[b][k] = __expf(att[b][k] - gmx[b]);
      s += att[b][k];
    }
    sum[b] = s;
  }
  for (int d = 32; d; d >>= 1)
    for (int b = 0; b < 8; ++b) sum[b] += __shfl_down(sum[b], d);
  __syncthreads();  // before reusing fred
  if ((tid & 63) == 0)
    for (int b = 0; b < 8; ++b) fred[b * 4 + wid] = sum[b];
  __syncthreads();
  for (int b = 0; b < 8; ++b) {
    float gs = (fred[b * 4] + fred[b * 4 + 1]) +
               (fred[b * 4 + 2] + fred[b * 4 + 3]);
    float inv = 1.0f / gs;
    if (f32m) {
      float* op = (float*)outv + ((size_t)(b << 10) + n) * NN;
      for (int k = 0; k < 4; ++k) op[tid + (k << 8)] = att[b][k] * inv;
    } else {
      bf16* op = (bf16*)outv + ((size_t)(b << 10) + n) * NN;
      for (int k = 0; k < 4; ++k)
        op[tid + (k << 8)] = __float2bfloat16(att[b][k] * inv);
    }
  }
}

extern "C" void kernel_launch(void* const* d_in, const int* in_sizes, int n_in,
                              void* d_out, int out_size, void* d_ws,
                              size_t ws_size, hipStream_t stream) {
  float* ws = (float*)d_ws;

  float* sq = ws;              // 8192
  float* wh1 = ws + 8192;      // 8192
  float* wh2 = ws + 16384;     // 8192
  float* thr = ws + 24576;     // 8
  float* flag = ws + 26656;    // 8
  float* isq = ws + 26664;     // 8192
  float* rsum = ws + 40960;    // 8192
  float* dcl = ws + 49152;     // 8192

  unsigned short* Hh = (unsigned short*)(ws + 65536);   // 524288 ushorts
  unsigned short* Hl = (unsigned short*)(ws + 327680);  // 524288 ushorts

  unsigned short* Wh = (unsigned short*)(ws + 589824);
  unsigned short* Wl = (unsigned short*)(ws + 4784128);
  unsigned short* WTh = (unsigned short*)(ws + 8978432);  // 16384 ushorts
  unsigned short* WTl = (unsigned short*)(ws + 8986624);  // 16384 ushorts
  unsigned short* Uh = (unsigned short*)(ws + 17367040);
  unsigned short* Ul = (unsigned short*)(ws + 21561344);
  float* Sf = ws + 25755648;  // 8388608 floats (final S)
  const size_t needed_fast = (25755648ull + 8388608ull) * 4ull;

  if (ws_size < needed_fast) {
    k_fill<<<dim3(2048), 256, 0, stream>>>((unsigned short*)d_out, out_size,
                                           (unsigned short)0xBF80);
    return;
  }

  k_setup<<<dim3(129), 256, 0, stream>>>((const unsigned short*)d_in[0], ws,
                                         flag, rsum);
  k_wt<<<dim3(64), 256, 0, stream>>>(d_in[1], flag, WTh, WTl);
  k_h<<<dim3(256), 256, 0, stream>>>(d_in[0], WTh, WTl, d_in[2], flag, Hh, Hl,
                                     sq, wh1, wh2);
  k_g0<<<dim3(512), 256, 0, stream>>>(Hh, Hl, sq, rsum);
  k_scal<<<dim3(32), 256, 0, stream>>>(rsum, dcl, isq);
  k_gw<<<dim3(512), 256, 0, stream>>>(Hh, Hl, sq, isq, Wh, Wl);
  k_mm1<<<dim3(576), 256, 0, stream>>>(Wh, Wl, Uh, Ul);
  k_mm2<<<dim3(576), 256, 0, stream>>>(Uh, Ul, Wh, Wl, dcl, isq, Sf);
  k_thr<<<dim3(BB), 256, 0, stream>>>(Sf, thr);
  k_so<<<dim3(NN), 256, 0, stream>>>(Sf, thr, wh1, wh2, flag, d_out);
}